// Round 1
// baseline (139.794 us; speedup 1.0000x reference)
//
#include <hip/hip_runtime.h>
#include <hip/hip_bf16.h>

// Shapes (fixed): B=4, H=56, W=56, C=256, NH=8, HD=32, KS=7, PAD=3
// tokens M = 4*56*56 = 12544. Padded k/v planes: [4][64][64][256] bf16,
// interior token (y,x) at plane row y+3, col x+3; border zeroed by prep.
//
// R12 lesson: LDS-free direct-fragment GEMM (per-wave global_load_dwordx4 of
// fragments, no barriers) REGRESSED 139.5 -> 151 us vs the staged version:
// duplicate fetches + thin per-wave VMEM dependency chain at ~2 blocks/CU
// can't cover L2 latency; global_load_lds staging decouples the queue.
// R14: proj re-tiled 128x128 -> 64x64 (196 -> 784 blocks): 196 blocks left
// 60 CUs idle and no block-overlap to hide the 8 barrier drains.
// R15 (this round): attn v-path de-LDS'd. PV consumption is per-lane-private
// (each lane reads only its own 16 ch x 7 cols), so vbuf staging (5 ds_write
// + 14 ds_read per ky) bought nothing; tl-window overlap (~2.8x) is L1-served.
// v now loaded directly: 14 per-lane b128 global loads issued before QK,
// consumed after softmax (latency hidden under ~700cy of QK+softmax); the
// k-prefetch is issued after them so consuming v never drains it (vmcnt>=5).
// LDS ops/wave-ky 38 -> 19, vmcnt-drain points 2 -> 1, LDS/block 12.1->6.85KB.

using frag_ab = __attribute__((ext_vector_type(8))) short;  // 8 bf16 (4 VGPRs)
using f32x4   = __attribute__((ext_vector_type(4))) float;  // 4 fp32 acc

typedef const __attribute__((address_space(1))) unsigned int* gas_u32;
typedef __attribute__((address_space(3))) unsigned int*       las_u32;

__device__ __forceinline__ void gl_lds16(const void* g, void* l) {
    // async global->LDS DMA, 16 B/lane; LDS dst = wave-uniform base + lane*16
    __builtin_amdgcn_global_load_lds((gas_u32)g, (las_u32)l, 16, 0, 0);
}

__device__ __forceinline__ float bflo(unsigned int u) { return __uint_as_float(u << 16); }
__device__ __forceinline__ float bfhi(unsigned int u) { return __uint_as_float(u & 0xffff0000u); }

// ================= fused prep =================
// blocks [0,3136):    x fp32 -> xb bf16 (float4/thread)
// blocks [3136,3904): w_qkv [256][768] -> wqkvT [768][256] bf16
// blocks [3904,4160): w_proj [256][256] -> wprojT [256][256] bf16
// blocks [4160,5120): zero the 960 border cols of each padded plane
__global__ __launch_bounds__(256) void prep(
    const float* __restrict__ x,      __hip_bfloat16* __restrict__ xb,
    const float* __restrict__ w_qkv,  __hip_bfloat16* __restrict__ wqkvT,
    const float* __restrict__ w_proj, __hip_bfloat16* __restrict__ wprojT,
    __hip_bfloat16* __restrict__ kp,  __hip_bfloat16* __restrict__ vp)
{
    const int bid = blockIdx.x;
    const int tid = threadIdx.x;
    if (bid < 3136) {
        const int i = bid * 256 + tid;            // over M*256/4 = 802816
        const float4 v = ((const float4*)x)[i];
        union { ushort4 u; __hip_bfloat16 h[4]; } o;
        o.h[0] = __float2bfloat16(v.x); o.h[1] = __float2bfloat16(v.y);
        o.h[2] = __float2bfloat16(v.z); o.h[3] = __float2bfloat16(v.w);
        ((ushort4*)xb)[i] = o.u;
    } else if (bid < 3904) {
        const int idx = (bid - 3136) * 256 + tid; // over 768*256
        const int k = idx & 255, n = idx >> 8;
        wqkvT[idx] = __float2bfloat16(w_qkv[k * 768 + n]);
    } else if (bid < 4160) {
        const int idx = (bid - 3904) * 256 + tid; // over 256*256
        const int k = idx & 255, n = idx >> 8;
        wprojT[idx] = __float2bfloat16(w_proj[k * 256 + n]);
    } else {
        const int u    = (bid - 4160) * 256 + tid;   // over 8*30720
        const int ip   = u / 30720;                  // img*2 + plane
        const int rem  = u - ip * 30720;
        const int cloc = rem >> 5;                   // 0..959 border cells
        const int q16  = rem & 31;                   // 16B chunk of 256 ch
        const int img  = ip >> 1;
        __hip_bfloat16* base = (ip & 1) ? vp : kp;
        int prow, pcol;
        if (cloc < 512) {                            // full pad rows 0-2,59-63
            const int r8 = cloc >> 6;
            prow = (r8 < 3) ? r8 : r8 + 56;
            pcol = cloc & 63;
        } else {                                     // side pads of rows 3..58
            const int c2 = cloc - 512;
            prow = 3 + (c2 >> 3);
            const int cc = c2 & 7;
            pcol = (cc < 3) ? cc : cc + 56;
        }
        *(uint4*)(base + (((size_t)(img * 64 + prow)) * 64 + pcol) * 256 + q16 * 8) =
            make_uint4(0u, 0u, 0u, 0u);
    }
}

// ================= 128x128 bf16 MFMA GEMM core (staged, R11-measured-best) ==
// 256 thr = 4 waves; wave w owns quadrant (w>>1, w&1) as 4x4 16x16x32 frags.
// Staging in fragment order via global_load_lds: wave w DMAs A row-blocks
// 2w,2w+1 and B row-blocks 2w,2w+1 (block = 16 rows x 32 k = 64 lanes x 16 B).
#define GEMM128_BODY(EPILOGUE)                                                  \
    constexpr int K = 256;                                                      \
    __shared__ frag_ab As[8][64];   /* 8 KB */                                  \
    __shared__ frag_ab Bs[8][64];   /* 8 KB */                                  \
    const int tid  = threadIdx.x;                                               \
    const int lane = tid & 63;                                                  \
    const int w    = tid >> 6;                                                  \
    const int wm   = w >> 1, wn = w & 1;                                        \
    const int m0 = blockIdx.y * 128;                                            \
    const int n0 = blockIdx.x * 128;                                            \
    const int lrow = lane & 15;                                                 \
    const int lk   = (lane >> 4) * 8;                                           \
    const __hip_bfloat16* gA0 = A  + (size_t)(m0 + (2*w+0)*16 + lrow) * K + lk; \
    const __hip_bfloat16* gA1 = A  + (size_t)(m0 + (2*w+1)*16 + lrow) * K + lk; \
    const __hip_bfloat16* gB0 = BT + (size_t)(n0 + (2*w+0)*16 + lrow) * K + lk; \
    const __hip_bfloat16* gB1 = BT + (size_t)(n0 + (2*w+1)*16 + lrow) * K + lk; \
    f32x4 acc[4][4] = {};                                                       \
    for (int k0 = 0; k0 < K; k0 += 32) {                                        \
        gl_lds16(gA0 + k0, &As[2*w+0][0]);                                      \
        gl_lds16(gA1 + k0, &As[2*w+1][0]);                                      \
        gl_lds16(gB0 + k0, &Bs[2*w+0][0]);                                      \
        gl_lds16(gB1 + k0, &Bs[2*w+1][0]);                                      \
        __syncthreads();                                                        \
        frag_ab af[4], bf[4];                                                   \
        _Pragma("unroll")                                                       \
        for (int i = 0; i < 4; ++i) { af[i] = As[wm*4+i][lane]; bf[i] = Bs[wn*4+i][lane]; } \
        _Pragma("unroll")                                                       \
        for (int i = 0; i < 4; ++i)                                             \
            _Pragma("unroll")                                                   \
            for (int j = 0; j < 4; ++j)                                         \
                acc[i][j] = __builtin_amdgcn_mfma_f32_16x16x32_bf16(af[i], bf[j], acc[i][j], 0, 0, 0); \
        __syncthreads();                                                        \
    }                                                                           \
    const int rbase = (lane >> 4) * 4;                                          \
    const int cbase = lane & 15;                                                \
    _Pragma("unroll")                                                           \
    for (int fi = 0; fi < 4; ++fi) {                                            \
        const int rm = m0 + wm * 64 + fi * 16 + rbase;                          \
        _Pragma("unroll")                                                       \
        for (int fj = 0; fj < 4; ++fj) {                                        \
            const int cn = n0 + wn * 64 + fj * 16 + cbase;                      \
            const float bv = bias[cn];                                          \
            _Pragma("unroll")                                                   \
            for (int r = 0; r < 4; ++r) {                                       \
                const int m = rm + r;                                           \
                const float val = acc[fi][fj][r] + bv;                          \
                EPILOGUE                                                        \
            }                                                                   \
        }                                                                       \
    }

// QKV GEMM: N=768; cols 0-255 -> qf fp32 (scaled); 256-511 -> kp; 512-767 -> vp
__global__ __launch_bounds__(256) void gemm_qkv(
    const __hip_bfloat16* __restrict__ A,
    const __hip_bfloat16* __restrict__ BT,
    const float* __restrict__ bias,
    float* __restrict__ qf,
    __hip_bfloat16* __restrict__ kp,
    __hip_bfloat16* __restrict__ vp,
    float qscale)
{
    GEMM128_BODY({
        const int sel = cn >> 8;                       // 0=q,1=k,2=v (uniform/block)
        if (sel == 0) {
            qf[(size_t)m * 256 + cn] = val * qscale;
        } else {
            const int c  = cn & 255;
            const int b  = m / 3136;
            const int r2 = m % 3136;
            const int yy = r2 / 56;
            const int xx = r2 % 56;
            __hip_bfloat16* dst = (sel == 1) ? kp : vp;
            dst[(((size_t)(b * 64 + yy + 3)) * 64 + (xx + 3)) * 256 + c] =
                __float2bfloat16(val);
        }
    })
}

// ===== proj GEMM, 64x64 tile (R2-validated structure; grid 4x196 = 784 ======
// blocks ~= 3/CU vs 196 with the 128-tile: proj is occupancy-bound, not
// MFMA-bound). 4 waves; wave w owns 32x32 quadrant (w>>1, w&1) as 2x2 frags;
// wave w stages A row-block w and B row-block w in fragment order.
__global__ __launch_bounds__(256) void gemm_proj(
    const __hip_bfloat16* __restrict__ A,
    const __hip_bfloat16* __restrict__ BT,
    const float* __restrict__ bias,
    float* __restrict__ C)
{
    constexpr int K = 256;
    __shared__ frag_ab As[4][64];   // 4 KB
    __shared__ frag_ab Bs[4][64];   // 4 KB

    const int tid  = threadIdx.x;
    const int lane = tid & 63;
    const int w    = tid >> 6;
    const int wm   = w >> 1, wn = w & 1;
    const int m0 = blockIdx.y * 64;
    const int n0 = blockIdx.x * 64;

    const int lrow = lane & 15;
    const int lk   = (lane >> 4) * 8;
    const __hip_bfloat16* gA = A  + (size_t)(m0 + w * 16 + lrow) * K + lk;
    const __hip_bfloat16* gB = BT + (size_t)(n0 + w * 16 + lrow) * K + lk;

    f32x4 acc[2][2] = {};

    for (int k0 = 0; k0 < K; k0 += 32) {
        gl_lds16(gA + k0, &As[w][0]);
        gl_lds16(gB + k0, &Bs[w][0]);
        __syncthreads();
        const frag_ab a0 = As[2 * wm + 0][lane];
        const frag_ab a1 = As[2 * wm + 1][lane];
        const frag_ab b0 = Bs[2 * wn + 0][lane];
        const frag_ab b1 = Bs[2 * wn + 1][lane];
        acc[0][0] = __builtin_amdgcn_mfma_f32_16x16x32_bf16(a0, b0, acc[0][0], 0, 0, 0);
        acc[0][1] = __builtin_amdgcn_mfma_f32_16x16x32_bf16(a0, b1, acc[0][1], 0, 0, 0);
        acc[1][0] = __builtin_amdgcn_mfma_f32_16x16x32_bf16(a1, b0, acc[1][0], 0, 0, 0);
        acc[1][1] = __builtin_amdgcn_mfma_f32_16x16x32_bf16(a1, b1, acc[1][1], 0, 0, 0);
        __syncthreads();
    }

    const int rbase = (lane >> 4) * 4;
    const int cbase = lane & 15;
    #pragma unroll
    for (int fi = 0; fi < 2; ++fi) {
        const int rm = m0 + wm * 32 + fi * 16 + rbase;
        #pragma unroll
        for (int fj = 0; fj < 2; ++fj) {
            const int cn = n0 + wn * 32 + fj * 16 + cbase;
            const float bv = bias[cn];
            #pragma unroll
            for (int r = 0; r < 4; ++r)
                C[(size_t)(rm + r) * 256 + cn] = acc[fi][fj][r] + bv;
        }
    }
}

// ================= neighborhood attention, single-pass online softmax =======
// ONE WAVE per block (64 thr) = 4 tokens x 8 heads x 2 half-heads; grid 3136.
// Staging registers are EXPLICIT SCALARS expanded by macro: R10's uint4 g[5]
// arrays captured by-pointer in lambdas defeated SROA -> the arrays lived in
// scratch (VGPR=68 but WRITE_SIZE=113 MB of spill evictions; fixing this in
// R11 removed attn from the top-5). Named scalars + rolled ky loop (#pragma
// unroll 1; full unroll hoists ~280 VGPRs of loads, measured R8/R9 ->
// 256-VGPR spill) keep per-iteration liveness bounded.
// NEVER set the launch_bounds min-waves arg here (R6: cap 84 -> 1.4 GB spill;
// R7: cap 128 -> 0.8 GB spill).
// XCD swizzle: blockIdx round-robins XCDs, so seg = (bid&7)*392 + (bid>>3)
// gives each XCD 392 contiguous segments (~2.2 MB k/v working set < 4 MB L2):
// measured FETCH 126 -> 26.6 MB (R9 -> R10).
// R15: k-row staged via LDS (cross-lane reuse through the 528-B-stride
// conflict-free layout); v consumed DIRECTLY from global per-lane (uint4
// va/vb arrays, fully-unrolled indices = SROA-safe): PV's pattern is
// lane-private so LDS staging of v was pure overhead, and the ~2.8x tl
// window overlap is L1-served. v loads issue before QK, k-prefetch after
// them, so PV's vmcnt waits (>=5) never drain the k-prefetch.
__global__ __launch_bounds__(64) void na2d_attn10(
    const float* __restrict__ qf,
    const __hip_bfloat16* __restrict__ kp,
    const __hip_bfloat16* __restrict__ vp,
    const float* __restrict__ rpb,
    __hip_bfloat16* __restrict__ out)
{
    const int lane = threadIdx.x;       // 0..63
    const int half = lane & 1;          // 16-ch half of a head
    const int h    = (lane >> 1) & 7;   // head
    const int tl   = (lane >> 4) & 3;   // token within 4-token segment

    const int bid = blockIdx.x;         // 0..3135
    const int seg = (bid & 7) * 392 + (bid >> 3);   // XCD-contiguous remap
    const int row = seg / 14;           // b*56 + y
    const int x0  = (seg % 14) * 4;     // 0..52
    const int b   = row / 56;
    const int y   = row % 56;
    const int t   = row * 56 + x0 + tl;
    const int prow0 = b * 64 + y;       // padded plane row for ky=0

    __shared__ __hip_bfloat16 kbuf[10 * 264];   // 5.28 KB, col stride 528 B
    __shared__ float srpb[8 * 49];

    for (int i = lane; i < 8 * 49; i += 64) srpb[i] = rpb[i];
    __syncthreads();                    // single-wave barrier: cheap

    // q: 16 fp32 channels (4 tokens' 256 ch are contiguous across the wave)
    float q[16];
    {
        const float4* qp = (const float4*)(qf + (size_t)t * 256 + h * 32 + half * 16);
        #pragma unroll
        for (int i = 0; i < 4; ++i) {
            const float4 v4 = qp[i];
            q[4 * i + 0] = v4.x; q[4 * i + 1] = v4.y;
            q[4 * i + 2] = v4.z; q[4 * i + 3] = v4.w;
        }
    }

    // LDS write offsets: unit=lane+i*64 -> col=2i+(lane>>5), j=lane&31
    // off_i = col*528 + j*16 = wroff + i*1056
    const int wroff = (lane >> 5) * 528 + (lane & 31) * 16;
    // LDS read base for this (tl,h,half); col offsets advance by 528/kx
    const int rdoff = tl * 528 + h * 64 + half * 32;

// load one padded row segment (10 cols x 256 ch bf16 = 5 KB) into 5 scalars
#define GLOAD(plane, ky, d0, d1, d2, d3, d4)                                    \
    do {                                                                        \
        const char* rb_ = (const char*)((plane) +                               \
            ((size_t)(prow0 + (ky)) * 64 + x0) * 256 + lane * 8);               \
        d0 = *(const uint4*)(rb_);                                              \
        d1 = *(const uint4*)(rb_ + 1024);                                       \
        d2 = *(const uint4*)(rb_ + 2048);                                       \
        d3 = *(const uint4*)(rb_ + 3072);                                       \
        d4 = *(const uint4*)(rb_ + 4096);                                       \
    } while (0)

#define LWRITE(buf, s0, s1, s2, s3, s4)                                         \
    do {                                                                        \
        char* wb_ = (char*)(buf) + wroff;                                       \
        *(uint4*)(wb_)        = s0;                                             \
        *(uint4*)(wb_ + 1056) = s1;                                             \
        *(uint4*)(wb_ + 2112) = s2;                                             \
        *(uint4*)(wb_ + 3168) = s3;                                             \
        *(uint4*)(wb_ + 4224) = s4;                                             \
    } while (0)

    const float* rp = &srpb[h * 49];
    float m = -1e30f, l = 0.f;
    float o[16] = {};

    uint4 k0, k1, k2, k3, k4;
    GLOAD(kp, 0, k0, k1, k2, k3, k4);

    #pragma unroll 1
    for (int ky = 0; ky < 7; ++ky) {
        LWRITE(kbuf, k0, k1, k2, k3, k4);       // waits vmcnt for k row only
        // ---- per-lane direct v loads: this lane's 16 ch for its 7 cols ----
        // col (plane) = x0 + tl + kx, ch base = h*32 + half*16; addresses are
        // independent of QK/softmax so latency hides under ~700cy of compute.
        const __hip_bfloat16* vrow = vp +
            ((size_t)(prow0 + ky) * 64 + x0 + tl) * 256 + h * 32 + half * 16;
        uint4 va[7], vb[7];
        #pragma unroll
        for (int kx = 0; kx < 7; ++kx) {
            va[kx] = *(const uint4*)(vrow + kx * 256);      // qd=0: ch 0..7
            vb[kx] = *(const uint4*)(vrow + kx * 256 + 8);  // qd=1: ch 8..15
        }
        // k-prefetch issued AFTER the v loads: consuming the newest v needs
        // only vmcnt(5), so these 5 loads stay in flight through PV.
        if (ky < 6) GLOAD(kp, ky + 1, k0, k1, k2, k3, k4);
        // ---- 7 row logits from kbuf ----
        float lg[7];
        #pragma unroll
        for (int kx = 0; kx < 7; ++kx) {
            const uint4* p = (const uint4*)((const char*)kbuf + rdoff + kx * 528);
            float s = 0.f;
            #pragma unroll
            for (int qd = 0; qd < 2; ++qd) {
                const uint4 wv = p[qd];
                const int o8 = qd * 8;
                s += q[o8 + 0] * bflo(wv.x) + q[o8 + 1] * bfhi(wv.x)
                   + q[o8 + 2] * bflo(wv.y) + q[o8 + 3] * bfhi(wv.y)
                   + q[o8 + 4] * bflo(wv.z) + q[o8 + 5] * bfhi(wv.z)
                   + q[o8 + 6] * bflo(wv.w) + q[o8 + 7] * bfhi(wv.w);
            }
            lg[kx] = s;
        }
        // ---- merge half-head partials + rpb ----
        #pragma unroll
        for (int kx = 0; kx < 7; ++kx) {
            lg[kx] += __shfl_xor(lg[kx], 1, 64);
            lg[kx] += rp[ky * 7 + kx];
        }
        // ---- online softmax update ----
        float rmax = lg[0];
        #pragma unroll
        for (int kx = 1; kx < 7; ++kx) rmax = fmaxf(rmax, lg[kx]);
        const float mnew  = fmaxf(m, rmax);
        const float alpha = __expf(m - mnew);   // ky=0: exp(-inf)=0
        m = mnew;
        l *= alpha;
        #pragma unroll
        for (int i = 0; i < 16; ++i) o[i] *= alpha;
        // ---- PV from direct-loaded registers ----
        #pragma unroll
        for (int kx = 0; kx < 7; ++kx) {
            const float pr = __expf(lg[kx] - mnew);
            l += pr;
            const uint4 w0 = va[kx];
            const uint4 w1 = vb[kx];
            o[0]  += pr * bflo(w0.x); o[1]  += pr * bfhi(w0.x);
            o[2]  += pr * bflo(w0.y); o[3]  += pr * bfhi(w0.y);
            o[4]  += pr * bflo(w0.z); o[5]  += pr * bfhi(w0.z);
            o[6]  += pr * bflo(w0.w); o[7]  += pr * bfhi(w0.w);
            o[8]  += pr * bflo(w1.x); o[9]  += pr * bfhi(w1.x);
            o[10] += pr * bflo(w1.y); o[11] += pr * bfhi(w1.y);
            o[12] += pr * bflo(w1.z); o[13] += pr * bfhi(w1.z);
            o[14] += pr * bflo(w1.w); o[15] += pr * bfhi(w1.w);
        }
    }
#undef GLOAD
#undef LWRITE

    // ---- store bf16 (feeds proj GEMM) ----
    const float inv = 1.f / l;
    union { uint4 u[2]; __hip_bfloat16 hh[16]; } ob;
    #pragma unroll
    for (int i = 0; i < 16; ++i) ob.hh[i] = __float2bfloat16(o[i] * inv);
    uint4* op = (uint4*)(out + (size_t)t * 256 + h * 32 + half * 16);
    op[0] = ob.u[0];
    op[1] = ob.u[1];
}

extern "C" void kernel_launch(void* const* d_in, const int* in_sizes, int n_in,
                              void* d_out, int out_size, void* d_ws, size_t ws_size,
                              hipStream_t stream)
{
    const float* x      = (const float*)d_in[0];   // (4,56,56,256)
    const float* w_qkv  = (const float*)d_in[1];   // (256,768)
    const float* b_qkv  = (const float*)d_in[2];   // (768,)
    const float* rpb    = (const float*)d_in[3];   // (8,49)
    const float* w_proj = (const float*)d_in[4];   // (256,256)
    const float* b_proj = (const float*)d_in[5];   // (256,)
    float* out = (float*)d_out;                    // (4,56,56,256) fp32

    const int M = 12544;

    char* wsp = (char*)d_ws;
    float* qf = (float*)wsp;                      wsp += (size_t)M * 256 * 4;   // 12.85 MB
    __hip_bfloat16* kp    = (__hip_bfloat16*)wsp; wsp += (size_t)4 * 64 * 64 * 256 * 2; // 8.39 MB
    __hip_bfloat16* vp    = (__hip_bfloat16*)wsp; wsp += (size_t)4 * 64 * 64 * 256 * 2; // 8.39 MB
    __hip_bfloat16* xb    = (__hip_bfloat16*)wsp; wsp += (size_t)M * 256 * 2;
    __hip_bfloat16* attnb = (__hip_bfloat16*)wsp; wsp += (size_t)M * 256 * 2;
    __hip_bfloat16* wqkvT = (__hip_bfloat16*)wsp; wsp += (size_t)768 * 256 * 2;
    __hip_bfloat16* wprojT= (__hip_bfloat16*)wsp; wsp += (size_t)256 * 256 * 2;

    const float scale = 0.17677669529663689f;  // 32^-0.5

    // fused prep: x->bf16, both weight transposes, pad-border zero of kp/vp
    prep<<<5120, 256, 0, stream>>>(x, xb, w_qkv, wqkvT, w_proj, wprojT, kp, vp);

    // qkv = xb @ wqkvT^T + b_qkv; q fp32 scaled -> qf; k/v bf16 -> padded planes
    gemm_qkv<<<dim3(6, 98), 256, 0, stream>>>(xb, wqkvT, b_qkv, qf, kp, vp, scale);

    // attention: 3136 blocks x 64 threads, v direct-from-global (R15)
    na2d_attn10<<<3136, 64, 0, stream>>>(qf, kp, vp, rpb, attnb);

    // out = attnb @ wprojT^T + b_proj (64-tile: 784 blocks ~= 3/CU)
    gemm_proj<<<dim3(4, 196), 256, 0, stream>>>(attnb, wprojT, b_proj, out);
}

// Round 2
// 133.025 us; speedup vs baseline: 1.0509x; 1.0509x over previous
//
#include <hip/hip_runtime.h>
#include <hip/hip_bf16.h>

// Shapes (fixed): B=4, H=56, W=56, C=256, NH=8, HD=32, KS=7, PAD=3
// tokens M = 4*56*56 = 12544. Padded k/v planes: [4][64][64][256] bf16,
// interior token (y,x) at plane row y+3, col x+3; border zeroed by prep.
//
// R12: LDS-free direct-fragment GEMM regressed (139.5 -> 151): staging via
// global_load_lds decouples the VMEM queue; keep it.
// R14: proj 64x64 tile (784 blocks) > 128x128 (196 blocks): occupancy.
// R15: attn v-path de-LDS'd (direct per-lane global loads). NEUTRAL ->
// attn is NOT LDS-throughput-bound; per-iter VALU (~510 instr) dominates.
// R16 (this round): attack attn VALU. (1) QK via v_dot2_f32_bf16 (guarded;
// 1 instr replaces 2 unpacks + 2 FMAs -> QK 224->56 instr/iter). (2) qf
// stored bf16 (enables packed q; logits are tiny so rounding is ~1e-4 rel;
// saves 12.8 MB of qf traffic). (3) PV + rescale in packed f32
// (ext_vector(2) -> v_pk_fma_f32 / v_pk_mul_f32).

using frag_ab = __attribute__((ext_vector_type(8))) short;  // 8 bf16 (4 VGPRs)
using f32x4   = __attribute__((ext_vector_type(4))) float;  // 4 fp32 acc
using f32x2   = __attribute__((ext_vector_type(2))) float;  // packed f32 pair

typedef const __attribute__((address_space(1))) unsigned int* gas_u32;
typedef __attribute__((address_space(3))) unsigned int*       las_u32;

__device__ __forceinline__ void gl_lds16(const void* g, void* l) {
    // async global->LDS DMA, 16 B/lane; LDS dst = wave-uniform base + lane*16
    __builtin_amdgcn_global_load_lds((gas_u32)g, (las_u32)l, 16, 0, 0);
}

__device__ __forceinline__ float bflo(unsigned int u) { return __uint_as_float(u << 16); }
__device__ __forceinline__ float bfhi(unsigned int u) { return __uint_as_float(u & 0xffff0000u); }

// unpack 2 packed bf16 -> packed f32 pair (2 VALU; feeds v_pk_* ops)
__device__ __forceinline__ f32x2 unpk2(unsigned int u) {
    f32x2 r; r.x = bflo(u); r.y = bfhi(u); return r;
}

#if defined(__has_builtin)
#if __has_builtin(__builtin_amdgcn_fdot2_f32_bf16)
#define HAVE_FDOT2_BF16 1
#endif
#endif

#ifdef HAVE_FDOT2_BF16
typedef __bf16 bf16x2 __attribute__((ext_vector_type(2)));
__device__ __forceinline__ float dot2bf(unsigned int a, unsigned int b, float c) {
    union { unsigned int u; bf16x2 h; } ua, ub;
    ua.u = a; ub.u = b;
    return __builtin_amdgcn_fdot2_f32_bf16(ua.h, ub.h, c, false);
}
#endif

// ================= fused prep =================
// blocks [0,3136):    x fp32 -> xb bf16 (float4/thread)
// blocks [3136,3904): w_qkv [256][768] -> wqkvT [768][256] bf16
// blocks [3904,4160): w_proj [256][256] -> wprojT [256][256] bf16
// blocks [4160,5120): zero the 960 border cols of each padded plane
__global__ __launch_bounds__(256) void prep(
    const float* __restrict__ x,      __hip_bfloat16* __restrict__ xb,
    const float* __restrict__ w_qkv,  __hip_bfloat16* __restrict__ wqkvT,
    const float* __restrict__ w_proj, __hip_bfloat16* __restrict__ wprojT,
    __hip_bfloat16* __restrict__ kp,  __hip_bfloat16* __restrict__ vp)
{
    const int bid = blockIdx.x;
    const int tid = threadIdx.x;
    if (bid < 3136) {
        const int i = bid * 256 + tid;            // over M*256/4 = 802816
        const float4 v = ((const float4*)x)[i];
        union { ushort4 u; __hip_bfloat16 h[4]; } o;
        o.h[0] = __float2bfloat16(v.x); o.h[1] = __float2bfloat16(v.y);
        o.h[2] = __float2bfloat16(v.z); o.h[3] = __float2bfloat16(v.w);
        ((ushort4*)xb)[i] = o.u;
    } else if (bid < 3904) {
        const int idx = (bid - 3136) * 256 + tid; // over 768*256
        const int k = idx & 255, n = idx >> 8;
        wqkvT[idx] = __float2bfloat16(w_qkv[k * 768 + n]);
    } else if (bid < 4160) {
        const int idx = (bid - 3904) * 256 + tid; // over 256*256
        const int k = idx & 255, n = idx >> 8;
        wprojT[idx] = __float2bfloat16(w_proj[k * 256 + n]);
    } else {
        const int u    = (bid - 4160) * 256 + tid;   // over 8*30720
        const int ip   = u / 30720;                  // img*2 + plane
        const int rem  = u - ip * 30720;
        const int cloc = rem >> 5;                   // 0..959 border cells
        const int q16  = rem & 31;                   // 16B chunk of 256 ch
        const int img  = ip >> 1;
        __hip_bfloat16* base = (ip & 1) ? vp : kp;
        int prow, pcol;
        if (cloc < 512) {                            // full pad rows 0-2,59-63
            const int r8 = cloc >> 6;
            prow = (r8 < 3) ? r8 : r8 + 56;
            pcol = cloc & 63;
        } else {                                     // side pads of rows 3..58
            const int c2 = cloc - 512;
            prow = 3 + (c2 >> 3);
            const int cc = c2 & 7;
            pcol = (cc < 3) ? cc : cc + 56;
        }
        *(uint4*)(base + (((size_t)(img * 64 + prow)) * 64 + pcol) * 256 + q16 * 8) =
            make_uint4(0u, 0u, 0u, 0u);
    }
}

// ================= 128x128 bf16 MFMA GEMM core (staged, R11-measured-best) ==
// 256 thr = 4 waves; wave w owns quadrant (w>>1, w&1) as 4x4 16x16x32 frags.
// Staging in fragment order via global_load_lds: wave w DMAs A row-blocks
// 2w,2w+1 and B row-blocks 2w,2w+1 (block = 16 rows x 32 k = 64 lanes x 16 B).
#define GEMM128_BODY(EPILOGUE)                                                  \
    constexpr int K = 256;                                                      \
    __shared__ frag_ab As[8][64];   /* 8 KB */                                  \
    __shared__ frag_ab Bs[8][64];   /* 8 KB */                                  \
    const int tid  = threadIdx.x;                                               \
    const int lane = tid & 63;                                                  \
    const int w    = tid >> 6;                                                  \
    const int wm   = w >> 1, wn = w & 1;                                        \
    const int m0 = blockIdx.y * 128;                                            \
    const int n0 = blockIdx.x * 128;                                            \
    const int lrow = lane & 15;                                                 \
    const int lk   = (lane >> 4) * 8;                                           \
    const __hip_bfloat16* gA0 = A  + (size_t)(m0 + (2*w+0)*16 + lrow) * K + lk; \
    const __hip_bfloat16* gA1 = A  + (size_t)(m0 + (2*w+1)*16 + lrow) * K + lk; \
    const __hip_bfloat16* gB0 = BT + (size_t)(n0 + (2*w+0)*16 + lrow) * K + lk; \
    const __hip_bfloat16* gB1 = BT + (size_t)(n0 + (2*w+1)*16 + lrow) * K + lk; \
    f32x4 acc[4][4] = {};                                                       \
    for (int k0 = 0; k0 < K; k0 += 32) {                                        \
        gl_lds16(gA0 + k0, &As[2*w+0][0]);                                      \
        gl_lds16(gA1 + k0, &As[2*w+1][0]);                                      \
        gl_lds16(gB0 + k0, &Bs[2*w+0][0]);                                      \
        gl_lds16(gB1 + k0, &Bs[2*w+1][0]);                                      \
        __syncthreads();                                                        \
        frag_ab af[4], bf[4];                                                   \
        _Pragma("unroll")                                                       \
        for (int i = 0; i < 4; ++i) { af[i] = As[wm*4+i][lane]; bf[i] = Bs[wn*4+i][lane]; } \
        _Pragma("unroll")                                                       \
        for (int i = 0; i < 4; ++i)                                             \
            _Pragma("unroll")                                                   \
            for (int j = 0; j < 4; ++j)                                         \
                acc[i][j] = __builtin_amdgcn_mfma_f32_16x16x32_bf16(af[i], bf[j], acc[i][j], 0, 0, 0); \
        __syncthreads();                                                        \
    }                                                                           \
    const int rbase = (lane >> 4) * 4;                                          \
    const int cbase = lane & 15;                                                \
    _Pragma("unroll")                                                           \
    for (int fi = 0; fi < 4; ++fi) {                                            \
        const int rm = m0 + wm * 64 + fi * 16 + rbase;                          \
        _Pragma("unroll")                                                       \
        for (int fj = 0; fj < 4; ++fj) {                                        \
            const int cn = n0 + wn * 64 + fj * 16 + cbase;                      \
            const float bv = bias[cn];                                          \
            _Pragma("unroll")                                                   \
            for (int r = 0; r < 4; ++r) {                                       \
                const int m = rm + r;                                           \
                const float val = acc[fi][fj][r] + bv;                          \
                EPILOGUE                                                        \
            }                                                                   \
        }                                                                       \
    }

// QKV GEMM: N=768; cols 0-255 -> qf bf16 (scaled); 256-511 -> kp; 512-767 -> vp
__global__ __launch_bounds__(256) void gemm_qkv(
    const __hip_bfloat16* __restrict__ A,
    const __hip_bfloat16* __restrict__ BT,
    const float* __restrict__ bias,
    __hip_bfloat16* __restrict__ qf,
    __hip_bfloat16* __restrict__ kp,
    __hip_bfloat16* __restrict__ vp,
    float qscale)
{
    GEMM128_BODY({
        const int sel = cn >> 8;                       // 0=q,1=k,2=v (uniform/block)
        if (sel == 0) {
            qf[(size_t)m * 256 + cn] = __float2bfloat16(val * qscale);
        } else {
            const int c  = cn & 255;
            const int b  = m / 3136;
            const int r2 = m % 3136;
            const int yy = r2 / 56;
            const int xx = r2 % 56;
            __hip_bfloat16* dst = (sel == 1) ? kp : vp;
            dst[(((size_t)(b * 64 + yy + 3)) * 64 + (xx + 3)) * 256 + c] =
                __float2bfloat16(val);
        }
    })
}

// ===== proj GEMM, 64x64 tile (R2-validated structure; grid 4x196 = 784 ======
__global__ __launch_bounds__(256) void gemm_proj(
    const __hip_bfloat16* __restrict__ A,
    const __hip_bfloat16* __restrict__ BT,
    const float* __restrict__ bias,
    float* __restrict__ C)
{
    constexpr int K = 256;
    __shared__ frag_ab As[4][64];   // 4 KB
    __shared__ frag_ab Bs[4][64];   // 4 KB

    const int tid  = threadIdx.x;
    const int lane = tid & 63;
    const int w    = tid >> 6;
    const int wm   = w >> 1, wn = w & 1;
    const int m0 = blockIdx.y * 64;
    const int n0 = blockIdx.x * 64;

    const int lrow = lane & 15;
    const int lk   = (lane >> 4) * 8;
    const __hip_bfloat16* gA = A  + (size_t)(m0 + w * 16 + lrow) * K + lk;
    const __hip_bfloat16* gB = BT + (size_t)(n0 + w * 16 + lrow) * K + lk;

    f32x4 acc[2][2] = {};

    for (int k0 = 0; k0 < K; k0 += 32) {
        gl_lds16(gA + k0, &As[w][0]);
        gl_lds16(gB + k0, &Bs[w][0]);
        __syncthreads();
        const frag_ab a0 = As[2 * wm + 0][lane];
        const frag_ab a1 = As[2 * wm + 1][lane];
        const frag_ab b0 = Bs[2 * wn + 0][lane];
        const frag_ab b1 = Bs[2 * wn + 1][lane];
        acc[0][0] = __builtin_amdgcn_mfma_f32_16x16x32_bf16(a0, b0, acc[0][0], 0, 0, 0);
        acc[0][1] = __builtin_amdgcn_mfma_f32_16x16x32_bf16(a0, b1, acc[0][1], 0, 0, 0);
        acc[1][0] = __builtin_amdgcn_mfma_f32_16x16x32_bf16(a1, b0, acc[1][0], 0, 0, 0);
        acc[1][1] = __builtin_amdgcn_mfma_f32_16x16x32_bf16(a1, b1, acc[1][1], 0, 0, 0);
        __syncthreads();
    }

    const int rbase = (lane >> 4) * 4;
    const int cbase = lane & 15;
    #pragma unroll
    for (int fi = 0; fi < 2; ++fi) {
        const int rm = m0 + wm * 32 + fi * 16 + rbase;
        #pragma unroll
        for (int fj = 0; fj < 2; ++fj) {
            const int cn = n0 + wn * 32 + fj * 16 + cbase;
            const float bv = bias[cn];
            #pragma unroll
            for (int r = 0; r < 4; ++r)
                C[(size_t)(rm + r) * 256 + cn] = acc[fi][fj][r] + bv;
        }
    }
}

// ================= neighborhood attention, single-pass online softmax =======
// ONE WAVE per block (64 thr) = 4 tokens x 8 heads x 2 half-heads; grid 3136.
// Staging registers are EXPLICIT SCALARS (R10/R11: arrays via lambda capture
// defeated SROA -> scratch spill). Rolled ky loop (#pragma unroll 1; full
// unroll -> 256-VGPR spill, R8/R9). NEVER set launch_bounds min-waves here
// (R6/R7: spill disasters).
// XCD swizzle: seg = (bid&7)*392 + (bid>>3): FETCH 126 -> 26.6 MB (R10).
// R15: v consumed directly from global (per-lane pattern is private; LDS
// staging of v was pure overhead) -- measured neutral, kept for the lower
// LDS footprint and single vmcnt-drain point.
// R16: q packed bf16 (from bf16 qf); QK via v_dot2_f32_bf16 when available
// (fallback: packed-f32 v_pk_fma); PV accumulate + rescale in packed f32.
__global__ __launch_bounds__(64) void na2d_attn11(
    const __hip_bfloat16* __restrict__ qf,
    const __hip_bfloat16* __restrict__ kp,
    const __hip_bfloat16* __restrict__ vp,
    const float* __restrict__ rpb,
    __hip_bfloat16* __restrict__ out)
{
    const int lane = threadIdx.x;       // 0..63
    const int half = lane & 1;          // 16-ch half of a head
    const int h    = (lane >> 1) & 7;   // head
    const int tl   = (lane >> 4) & 3;   // token within 4-token segment

    const int bid = blockIdx.x;         // 0..3135
    const int seg = (bid & 7) * 392 + (bid >> 3);   // XCD-contiguous remap
    const int row = seg / 14;           // b*56 + y
    const int x0  = (seg % 14) * 4;     // 0..52
    const int b   = row / 56;
    const int y   = row % 56;
    const int t   = row * 56 + x0 + tl;
    const int prow0 = b * 64 + y;       // padded plane row for ky=0

    __shared__ __hip_bfloat16 kbuf[10 * 264];   // 5.28 KB, col stride 528 B
    __shared__ float srpb[8 * 49];

    for (int i = lane; i < 8 * 49; i += 64) srpb[i] = rpb[i];
    __syncthreads();                    // single-wave barrier: cheap

    // q: 16 bf16 channels, kept PACKED (8 uints = 8 VGPRs)
    unsigned int qpk[8];
    {
        const uint4* qp = (const uint4*)(qf + (size_t)t * 256 + h * 32 + half * 16);
        const uint4 qa = qp[0], qb = qp[1];
        qpk[0] = qa.x; qpk[1] = qa.y; qpk[2] = qa.z; qpk[3] = qa.w;
        qpk[4] = qb.x; qpk[5] = qb.y; qpk[6] = qb.z; qpk[7] = qb.w;
    }
#ifndef HAVE_FDOT2_BF16
    f32x2 q2[8];
    #pragma unroll
    for (int i = 0; i < 8; ++i) q2[i] = unpk2(qpk[i]);
#endif

    // LDS write offsets: unit=lane+i*64 -> col=2i+(lane>>5), j=lane&31
    const int wroff = (lane >> 5) * 528 + (lane & 31) * 16;
    // LDS read base for this (tl,h,half); col offsets advance by 528/kx
    const int rdoff = tl * 528 + h * 64 + half * 32;

// load one padded row segment (10 cols x 256 ch bf16 = 5 KB) into 5 scalars
#define GLOAD(plane, ky, d0, d1, d2, d3, d4)                                    \
    do {                                                                        \
        const char* rb_ = (const char*)((plane) +                               \
            ((size_t)(prow0 + (ky)) * 64 + x0) * 256 + lane * 8);               \
        d0 = *(const uint4*)(rb_);                                              \
        d1 = *(const uint4*)(rb_ + 1024);                                       \
        d2 = *(const uint4*)(rb_ + 2048);                                       \
        d3 = *(const uint4*)(rb_ + 3072);                                       \
        d4 = *(const uint4*)(rb_ + 4096);                                       \
    } while (0)

#define LWRITE(buf, s0, s1, s2, s3, s4)                                         \
    do {                                                                        \
        char* wb_ = (char*)(buf) + wroff;                                       \
        *(uint4*)(wb_)        = s0;                                             \
        *(uint4*)(wb_ + 1056) = s1;                                             \
        *(uint4*)(wb_ + 2112) = s2;                                             \
        *(uint4*)(wb_ + 3168) = s3;                                             \
        *(uint4*)(wb_ + 4224) = s4;                                             \
    } while (0)

    const float* rp = &srpb[h * 49];
    float m = -1e30f, l = 0.f;
    f32x2 o2[8] = {};

    uint4 k0, k1, k2, k3, k4;
    GLOAD(kp, 0, k0, k1, k2, k3, k4);

    #pragma unroll 1
    for (int ky = 0; ky < 7; ++ky) {
        LWRITE(kbuf, k0, k1, k2, k3, k4);       // waits vmcnt for k row only
        // ---- per-lane direct v loads: this lane's 16 ch for its 7 cols ----
        const __hip_bfloat16* vrow = vp +
            ((size_t)(prow0 + ky) * 64 + x0 + tl) * 256 + h * 32 + half * 16;
        uint4 va[7], vb[7];
        #pragma unroll
        for (int kx = 0; kx < 7; ++kx) {
            va[kx] = *(const uint4*)(vrow + kx * 256);      // ch 0..7
            vb[kx] = *(const uint4*)(vrow + kx * 256 + 8);  // ch 8..15
        }
        // k-prefetch AFTER v loads: PV's vmcnt waits never drain it
        if (ky < 6) GLOAD(kp, ky + 1, k0, k1, k2, k3, k4);
        // ---- 7 row logits from kbuf ----
        float lg[7];
        #pragma unroll
        for (int kx = 0; kx < 7; ++kx) {
            const uint4* p = (const uint4*)((const char*)kbuf + rdoff + kx * 528);
            const uint4 w0 = p[0];
            const uint4 w1 = p[1];
#ifdef HAVE_FDOT2_BF16
            float s = 0.f;
            s = dot2bf(qpk[0], w0.x, s);
            s = dot2bf(qpk[1], w0.y, s);
            s = dot2bf(qpk[2], w0.z, s);
            s = dot2bf(qpk[3], w0.w, s);
            s = dot2bf(qpk[4], w1.x, s);
            s = dot2bf(qpk[5], w1.y, s);
            s = dot2bf(qpk[6], w1.z, s);
            s = dot2bf(qpk[7], w1.w, s);
#else
            f32x2 s2 = {0.f, 0.f};
            s2 += q2[0] * unpk2(w0.x);
            s2 += q2[1] * unpk2(w0.y);
            s2 += q2[2] * unpk2(w0.z);
            s2 += q2[3] * unpk2(w0.w);
            s2 += q2[4] * unpk2(w1.x);
            s2 += q2[5] * unpk2(w1.y);
            s2 += q2[6] * unpk2(w1.z);
            s2 += q2[7] * unpk2(w1.w);
            const float s = s2.x + s2.y;
#endif
            lg[kx] = s;
        }
        // ---- merge half-head partials + rpb ----
        #pragma unroll
        for (int kx = 0; kx < 7; ++kx) {
            lg[kx] += __shfl_xor(lg[kx], 1, 64);
            lg[kx] += rp[ky * 7 + kx];
        }
        // ---- online softmax update ----
        float rmax = lg[0];
        #pragma unroll
        for (int kx = 1; kx < 7; ++kx) rmax = fmaxf(rmax, lg[kx]);
        const float mnew  = fmaxf(m, rmax);
        const float alpha = __expf(m - mnew);   // ky=0: exp(-inf)=0
        m = mnew;
        l *= alpha;
        const f32x2 alpha2 = {alpha, alpha};
        #pragma unroll
        for (int i = 0; i < 8; ++i) o2[i] *= alpha2;
        // ---- PV from direct-loaded registers, packed-f32 accumulate ----
        #pragma unroll
        for (int kx = 0; kx < 7; ++kx) {
            const float pr = __expf(lg[kx] - mnew);
            l += pr;
            const f32x2 pr2 = {pr, pr};
            const uint4 w0 = va[kx];
            const uint4 w1 = vb[kx];
            o2[0] += pr2 * unpk2(w0.x);
            o2[1] += pr2 * unpk2(w0.y);
            o2[2] += pr2 * unpk2(w0.z);
            o2[3] += pr2 * unpk2(w0.w);
            o2[4] += pr2 * unpk2(w1.x);
            o2[5] += pr2 * unpk2(w1.y);
            o2[6] += pr2 * unpk2(w1.z);
            o2[7] += pr2 * unpk2(w1.w);
        }
    }
#undef GLOAD
#undef LWRITE

    // ---- store bf16 (feeds proj GEMM) ----
    const float inv = 1.f / l;
    union { uint4 u[2]; __hip_bfloat16 hh[16]; } ob;
    #pragma unroll
    for (int i = 0; i < 8; ++i) {
        ob.hh[2 * i + 0] = __float2bfloat16(o2[i].x * inv);
        ob.hh[2 * i + 1] = __float2bfloat16(o2[i].y * inv);
    }
    uint4* op = (uint4*)(out + (size_t)t * 256 + h * 32 + half * 16);
    op[0] = ob.u[0];
    op[1] = ob.u[1];
}

extern "C" void kernel_launch(void* const* d_in, const int* in_sizes, int n_in,
                              void* d_out, int out_size, void* d_ws, size_t ws_size,
                              hipStream_t stream)
{
    const float* x      = (const float*)d_in[0];   // (4,56,56,256)
    const float* w_qkv  = (const float*)d_in[1];   // (256,768)
    const float* b_qkv  = (const float*)d_in[2];   // (768,)
    const float* rpb    = (const float*)d_in[3];   // (8,49)
    const float* w_proj = (const float*)d_in[4];   // (256,256)
    const float* b_proj = (const float*)d_in[5];   // (256,)
    float* out = (float*)d_out;                    // (4,56,56,256) fp32

    const int M = 12544;

    char* wsp = (char*)d_ws;
    __hip_bfloat16* qf    = (__hip_bfloat16*)wsp; wsp += (size_t)M * 256 * 2;   // 6.4 MB (bf16 now)
    __hip_bfloat16* kp    = (__hip_bfloat16*)wsp; wsp += (size_t)4 * 64 * 64 * 256 * 2; // 8.39 MB
    __hip_bfloat16* vp    = (__hip_bfloat16*)wsp; wsp += (size_t)4 * 64 * 64 * 256 * 2; // 8.39 MB
    __hip_bfloat16* xb    = (__hip_bfloat16*)wsp; wsp += (size_t)M * 256 * 2;
    __hip_bfloat16* attnb = (__hip_bfloat16*)wsp; wsp += (size_t)M * 256 * 2;
    __hip_bfloat16* wqkvT = (__hip_bfloat16*)wsp; wsp += (size_t)768 * 256 * 2;
    __hip_bfloat16* wprojT= (__hip_bfloat16*)wsp; wsp += (size_t)256 * 256 * 2;

    const float scale = 0.17677669529663689f;  // 32^-0.5

    // fused prep: x->bf16, both weight transposes, pad-border zero of kp/vp
    prep<<<5120, 256, 0, stream>>>(x, xb, w_qkv, wqkvT, w_proj, wprojT, kp, vp);

    // qkv = xb @ wqkvT^T + b_qkv; q bf16 scaled -> qf; k/v bf16 -> padded planes
    gemm_qkv<<<dim3(6, 98), 256, 0, stream>>>(xb, wqkvT, b_qkv, qf, kp, vp, scale);

    // attention: 3136 blocks x 64 threads; dot2 QK + packed-f32 PV (R16)
    na2d_attn11<<<3136, 64, 0, stream>>>(qf, kp, vp, rpb, attnb);

    // out = attnb @ wprojT^T + b_proj (64-tile: 784 blocks ~= 3/CU)
    gemm_proj<<<dim3(4, 196), 256, 0, stream>>>(attnb, wprojT, b_proj, out);
}